// Round 1
// baseline (988.021 us; speedup 1.0000x reference)
//
#include <hip/hip_runtime.h>
#include <math.h>

// out = tanh(x @ (exp(s)[:,None] * V) + bias)
// BATCH=1048576, IN_DIM=128, UNITS=128, all fp32.
//
// Strategy: memory-bound streaming GEMM. x converted to fp16 (RTN) in
// registers, W converted to fp16 (RTN) once in setup; single-pass
// mfma_f32_16x16x32_f16. Error budget: x-RTN alone measured 0.0039 absmax;
// W-RTN adds a similar independent term -> ~0.006-0.012 vs 2e-2 threshold.
// B fragments live entirely in registers (32 VGPRs); no LDS, no barriers.
// 4 waves/SIMD occupancy (launch_bounds(256,4)) to hide HBM latency.

typedef _Float16 half8 __attribute__((ext_vector_type(8)));
typedef float float4v __attribute__((ext_vector_type(4)));

#define RWF_BATCH   1048576
#define RWF_K       128
#define RWF_N       128
#define RWF_TILE_M  64
#define RWF_NTILES  (RWF_BATCH / RWF_TILE_M)   // 16384
#define RWF_GRID    2048

// ---------------------------------------------------------------------------
// Setup: W = exp(s)[:,None] * V  -> transposed fp16 in d_ws.
// ws layout (as _Float16*): [0,16384): wT[n*128+k].
// ---------------------------------------------------------------------------
__global__ void rwf_setup_w(const float* __restrict__ s,
                            const float* __restrict__ V,
                            _Float16* __restrict__ wsT) {
    int t = blockIdx.x * blockDim.x + threadIdx.x;   // 0..16383
    int i = t >> 7;     // k index (row of V / index into s)
    int j = t & 127;    // n index (col of V)
    float w = expf(s[i]) * V[t];
    wsT[j * 128 + i] = (_Float16)w;                  // RTN
}

// ---------------------------------------------------------------------------
// Main kernel. Block = 256 threads (4 waves). Block tile: 64 rows x 128 cols.
// Each wave owns the FULL 64 rows x a 32-col quarter (wave*32).
//   -> B frags: 4 ksteps x 2 ntiles = 8 half8 = 32 VGPRs (vs 64 before).
//   -> x rows are loaded by all 4 waves; L1 (same CU, same tile) absorbs it.
// Per wave: 4 m-tiles x 2 n-tiles of 16x16, K=128 in 4 MFMA k-steps.
// ---------------------------------------------------------------------------
__global__ __launch_bounds__(256, 4) void rwf_main(
    const float* __restrict__ x,
    const float* __restrict__ bias,
    const _Float16* __restrict__ wsT,
    float* __restrict__ out)
{
    const int lane = threadIdx.x & 63;
    const int wave = threadIdx.x >> 6;     // 0..3
    const int ln15 = lane & 15;
    const int quad = lane >> 4;            // 0..3
    const int wcol = wave * 32;            // col quarter for this wave

    // --- B fragments, held in registers for the whole kernel -------------
    // B-frag layout for 16x16x32: lane holds B[k = quad*8+j][n = ln15].
    // wsT is stored [n][k], so 8 consecutive k's = one 16B load.
    half8 bh[4][2];   // [kstep][ntile]
    #pragma unroll
    for (int ks = 0; ks < 4; ++ks) {
        #pragma unroll
        for (int nt = 0; nt < 2; ++nt) {
            int n = wcol + nt * 16 + ln15;
            bh[ks][nt] = *(const half8*)(wsT + n * 128 + ks * 32 + quad * 8);
        }
    }

    // bias per n-tile (col = wcol + nt*16 + ln15). Folded into MFMA C-init:
    // C/D frag layout col = ln15 for all 4 regs -> all regs share bias[col].
    float bv[2];
    #pragma unroll
    for (int nt = 0; nt < 2; ++nt) bv[nt] = bias[wcol + nt * 16 + ln15];

    const int laneoff = ln15 * RWF_K + quad * 8;   // A-frag lane offset

    for (int tile = blockIdx.x; tile < RWF_NTILES; tile += gridDim.x) {
        const float* xb = x + (size_t)tile * RWF_TILE_M * RWF_K;

        float4v acc[4][2];
        #pragma unroll
        for (int mt = 0; mt < 4; ++mt)
            #pragma unroll
            for (int nt = 0; nt < 2; ++nt) {
                acc[mt][nt][0] = bv[nt];
                acc[mt][nt][1] = bv[nt];
                acc[mt][nt][2] = bv[nt];
                acc[mt][nt][3] = bv[nt];
            }

        #pragma unroll
        for (int ks = 0; ks < 4; ++ks) {
            // A-frag: lane holds x[row = mt*16+ln15][k = ks*32+quad*8+j],
            // 8 consecutive floats -> 2 x dwordx4, convert to fp16 RTN.
            half8 a[4];
            #pragma unroll
            for (int mt = 0; mt < 4; ++mt) {
                const float* p = xb + mt * 16 * RWF_K + ks * 32 + laneoff;
                float4v u0 = *(const float4v*)p;
                float4v u1 = *(const float4v*)(p + 4);
                half8 av;
                av[0] = (_Float16)u0[0]; av[1] = (_Float16)u0[1];
                av[2] = (_Float16)u0[2]; av[3] = (_Float16)u0[3];
                av[4] = (_Float16)u1[0]; av[5] = (_Float16)u1[1];
                av[6] = (_Float16)u1[2]; av[7] = (_Float16)u1[3];
                a[mt] = av;
            }
            #pragma unroll
            for (int mt = 0; mt < 4; ++mt) {
                #pragma unroll
                for (int nt = 0; nt < 2; ++nt) {
                    acc[mt][nt] = __builtin_amdgcn_mfma_f32_16x16x32_f16(
                        a[mt], bh[ks][nt], acc[mt][nt], 0, 0, 0);
                }
            }
        }

        // --- epilogue: tanh + store (bias already folded into acc) -------
        // C/D layout: col = ln15, row = quad*4 + r  [m89-verified].
        const int row0 = tile * RWF_TILE_M + quad * 4;
        const int col0 = wcol + ln15;
        #pragma unroll
        for (int mt = 0; mt < 4; ++mt) {
            #pragma unroll
            for (int nt = 0; nt < 2; ++nt) {
                #pragma unroll
                for (int r = 0; r < 4; ++r) {
                    float z = acc[mt][nt][r];
                    // tanh(z) = 1 - 2/(e^{2z}+1); saturates via inf math.
                    float e = __expf(2.0f * z);
                    float o = 1.0f - 2.0f * __builtin_amdgcn_rcpf(e + 1.0f);
                    __builtin_nontemporal_store(
                        o, out + (size_t)(row0 + mt * 16 + r) * RWF_N
                               + col0 + nt * 16);
                }
            }
        }
    }
}

// ---------------------------------------------------------------------------
extern "C" void kernel_launch(void* const* d_in, const int* in_sizes, int n_in,
                              void* d_out, int out_size, void* d_ws, size_t ws_size,
                              hipStream_t stream) {
    const float* x    = (const float*)d_in[0];
    const float* s    = (const float*)d_in[1];
    const float* V    = (const float*)d_in[2];
    const float* bias = (const float*)d_in[3];
    float* out        = (float*)d_out;
    _Float16* wsT     = (_Float16*)d_ws;   // 16384 halves = 32 KiB

    // Setup runs every call: d_ws is re-poisoned before each timed launch.
    rwf_setup_w<<<(RWF_K * RWF_N) / 256, 256, 0, stream>>>(s, V, wsT);
    rwf_main<<<RWF_GRID, 256, 0, stream>>>(x, bias, wsT, out);
}

// Round 2
// 862.434 us; speedup vs baseline: 1.1456x; 1.1456x over previous
//
#include <hip/hip_runtime.h>
#include <math.h>

// out = tanh(x @ (exp(s)[:,None] * V) + bias)
// BATCH=1048576, IN_DIM=128, UNITS=128, all fp32.
//
// Strategy: latency-bound -> async-pipelined streaming GEMM.
// x is staged global->LDS via __builtin_amdgcn_global_load_lds (1 KB per
// wave-instr, perfectly coalesced), double-buffered with counted
// s_waitcnt vmcnt(4) + raw s_barrier so the next tile's 16 KB stays in
// flight across the barrier (T3/T4 minimum-2-phase recipe). A-frags are
// read from LDS (ds_read_b128 x2), converted to fp16 RTN, single-pass
// mfma_f32_16x16x32_f16 against register-resident fp16 W (exact-RTN).
// absmax budget: x-RTN + W-RTN measured 0.0059 vs 2e-2 threshold.
// No read-swizzle: we are BW/latency-bound; LDS conflicts (~2x over b128
// floor) are far off the critical path at this tile size.

typedef _Float16 half8 __attribute__((ext_vector_type(8)));
typedef float float4v __attribute__((ext_vector_type(4)));

#define RWF_BATCH   1048576
#define RWF_K       128
#define RWF_N       128
#define RWF_TILE_M  32
#define RWF_NTILES  (RWF_BATCH / RWF_TILE_M)   // 32768
#define RWF_GRID    2048
#define RWF_TPB     (RWF_NTILES / RWF_GRID)    // 16 tiles per block

// ---------------------------------------------------------------------------
// Setup: W = exp(s)[:,None] * V  -> transposed fp16 in d_ws.
// ws layout (as _Float16*): [0,16384): wT[n*128+k].
// ---------------------------------------------------------------------------
__global__ void rwf_setup_w(const float* __restrict__ s,
                            const float* __restrict__ V,
                            _Float16* __restrict__ wsT) {
    int t = blockIdx.x * blockDim.x + threadIdx.x;   // 0..16383
    int i = t >> 7;     // k index (row of V / index into s)
    int j = t & 127;    // n index (col of V)
    float w = expf(s[i]) * V[t];
    wsT[j * 128 + i] = (_Float16)w;                  // RTN
}

// ---------------------------------------------------------------------------
// Main kernel. Block = 256 threads (4 waves). Block tile: 32 rows x 128 cols
// (16 KB of x). Each wave: full 32 rows x a 32-col quarter.
//   B frags: 4 ksteps x 2 ntiles = 8 half8 = 32 VGPRs, loaded once.
//   Per tile per wave: 4 global_load_lds (1 KB each), 16 ds_read_b128,
//   8 MFMA, 16 tanh+store.
// Pipeline (prefetch depth 2 buffers):
//   prologue: STAGE(buf0,t0); STAGE(buf1,t1)
//   iter i:   vmcnt(4)  -> tile i's stage done, tile i+1's 4 loads in flight
//             barrier   -> all waves agree buf[i&1] is valid
//             compute+store from buf[i&1]
//             barrier   -> all waves done reading buf[i&1]
//             STAGE(buf[i&1], t_{i+2})   (gated; never drain vmcnt to 0)
// ---------------------------------------------------------------------------
__global__ __launch_bounds__(256, 4) void rwf_main(
    const float* __restrict__ x,
    const float* __restrict__ bias,
    const _Float16* __restrict__ wsT,
    float* __restrict__ out)
{
    __shared__ float lds[2][RWF_TILE_M * RWF_K];   // 2 x 16 KB

    const int lane = threadIdx.x & 63;
    const int wave = threadIdx.x >> 6;     // 0..3
    const int ln15 = lane & 15;
    const int quad = lane >> 4;            // 0..3
    const int wcol = wave * 32;            // col quarter for this wave

    // --- B fragments, registers for the whole kernel ---------------------
    // B-frag layout for 16x16x32: lane holds B[k = quad*8+j][n = ln15].
    half8 bh[4][2];   // [kstep][ntile]
    #pragma unroll
    for (int ks = 0; ks < 4; ++ks) {
        #pragma unroll
        for (int nt = 0; nt < 2; ++nt) {
            int n = wcol + nt * 16 + ln15;
            bh[ks][nt] = *(const half8*)(wsT + n * 128 + ks * 32 + quad * 8);
        }
    }

    // bias per n-tile, folded into the MFMA C-init (col = ln15 for all regs)
    float bv[2];
    #pragma unroll
    for (int nt = 0; nt < 2; ++nt) bv[nt] = bias[wcol + nt * 16 + ln15];

// 16 chunks of 1 KB per tile; wave w issues chunks w*4 .. w*4+3.
// global source is per-lane (lane*16 B); LDS dest is wave-uniform base.
#define RWF_STAGE(buf_, tile_) do {                                          \
    const float* _src = x + (size_t)(tile_) * (RWF_TILE_M * RWF_K);          \
    _Pragma("unroll")                                                        \
    for (int _j = 0; _j < 4; ++_j) {                                         \
        const int _c = wave * 4 + _j;                                        \
        __builtin_amdgcn_global_load_lds(                                    \
            (const __attribute__((address_space(1))) void*)                  \
                (_src + _c * 256 + lane * 4),                                \
            (__attribute__((address_space(3))) void*)                        \
                (&lds[(buf_)][_c * 256]),                                    \
            16, 0, 0);                                                       \
    }                                                                        \
} while (0)

    const int t0 = blockIdx.x * RWF_TPB;

    RWF_STAGE(0, t0);
    RWF_STAGE(1, t0 + 1);

    for (int i = 0; i < RWF_TPB; ++i) {
        const int cur = i & 1;
        const int t   = t0 + i;

        // Tile i's 4 stage-loads done (and prior stores drained); tile i+1's
        // 4 loads remain in flight across the barrier. Never vmcnt(0).
        asm volatile("s_waitcnt vmcnt(4)" ::: "memory");
        __builtin_amdgcn_s_barrier();

        float4v acc[2][2];
        #pragma unroll
        for (int mt = 0; mt < 2; ++mt)
            #pragma unroll
            for (int nt = 0; nt < 2; ++nt) {
                acc[mt][nt][0] = bv[nt];
                acc[mt][nt][1] = bv[nt];
                acc[mt][nt][2] = bv[nt];
                acc[mt][nt][3] = bv[nt];
            }

        #pragma unroll
        for (int ks = 0; ks < 4; ++ks) {
            // A-frag: lane holds x[row = mt*16+ln15][k = ks*32+quad*8+j]
            half8 a[2];
            #pragma unroll
            for (int mt = 0; mt < 2; ++mt) {
                const float* p = &lds[cur][(mt * 16 + ln15) * RWF_K
                                           + ks * 32 + quad * 8];
                float4v u0 = *(const float4v*)p;
                float4v u1 = *(const float4v*)(p + 4);
                half8 av;
                av[0] = (_Float16)u0[0]; av[1] = (_Float16)u0[1];
                av[2] = (_Float16)u0[2]; av[3] = (_Float16)u0[3];
                av[4] = (_Float16)u1[0]; av[5] = (_Float16)u1[1];
                av[6] = (_Float16)u1[2]; av[7] = (_Float16)u1[3];
                a[mt] = av;
            }
            #pragma unroll
            for (int mt = 0; mt < 2; ++mt)
                #pragma unroll
                for (int nt = 0; nt < 2; ++nt)
                    acc[mt][nt] = __builtin_amdgcn_mfma_f32_16x16x32_f16(
                        a[mt], bh[ks][nt], acc[mt][nt], 0, 0, 0);
        }

        // --- epilogue: tanh + store (bias already in acc) ----------------
        // C/D layout: col = ln15, row = quad*4 + r  [m89-verified].
        // Store pattern: 4 segments x 64 B per instr -> full cache lines.
        const int row0 = t * RWF_TILE_M + quad * 4;
        const int col0 = wcol + ln15;
        #pragma unroll
        for (int mt = 0; mt < 2; ++mt) {
            #pragma unroll
            for (int nt = 0; nt < 2; ++nt) {
                #pragma unroll
                for (int r = 0; r < 4; ++r) {
                    float z = acc[mt][nt][r];
                    // tanh(z) = 1 - 2/(e^{2z}+1); saturates via inf math.
                    float e = __expf(2.0f * z);
                    float o = 1.0f - 2.0f * __builtin_amdgcn_rcpf(e + 1.0f);
                    out[(size_t)(row0 + mt * 16 + r) * RWF_N
                        + col0 + nt * 16] = o;
                }
            }
        }

        // Keep stores on this side of the barrier (vmcnt accounting).
        asm volatile("" ::: "memory");
        __builtin_amdgcn_s_barrier();   // all waves done reading buf[cur]

        if (i + 2 < RWF_TPB) RWF_STAGE(cur, t + 2);
    }
#undef RWF_STAGE
}

// ---------------------------------------------------------------------------
extern "C" void kernel_launch(void* const* d_in, const int* in_sizes, int n_in,
                              void* d_out, int out_size, void* d_ws, size_t ws_size,
                              hipStream_t stream) {
    const float* x    = (const float*)d_in[0];
    const float* s    = (const float*)d_in[1];
    const float* V    = (const float*)d_in[2];
    const float* bias = (const float*)d_in[3];
    float* out        = (float*)d_out;
    _Float16* wsT     = (_Float16*)d_ws;   // 16384 halves = 32 KiB

    // Setup runs every call: d_ws is re-poisoned before each timed launch.
    rwf_setup_w<<<(RWF_K * RWF_N) / 256, 256, 0, stream>>>(s, V, wsT);
    rwf_main<<<RWF_GRID, 256, 0, stream>>>(x, bias, wsT, out);
}